// Round 4
// baseline (133.310 us; speedup 1.0000x reference)
//
#include <hip/hip_runtime.h>
#include <hip/hip_bf16.h>

#define B_   4
#define C_   256
#define CO_  256
#define H_   64
#define W_   64
#define HW_  4096

typedef __attribute__((ext_vector_type(8))) short short8;
typedef __attribute__((ext_vector_type(4))) float f32x4;

static __device__ __forceinline__ unsigned short f2bf(float f) {
    unsigned u = __builtin_bit_cast(unsigned, f);
    unsigned r = (u + 0x7fffu + ((u >> 16) & 1u)) >> 16;
    return (unsigned short)r;
}
static __device__ __forceinline__ float bf2f(unsigned short s) {
    unsigned u = ((unsigned)s) << 16;
    return __builtin_bit_cast(float, u);
}

// ---------------- K1: NCHW f32 -> NHWC bf16 transpose (32hw x 128c tiles) ------------
__global__ void k_transpose(const float* __restrict__ x, unsigned short* __restrict__ xT)
{
    __shared__ float t[32][136];
    int bid = blockIdx.x;            // 1024 = b(4) * hwT(128) * cT(2)
    int b   = bid >> 8;
    int rem = bid & 255;
    int hwT = rem >> 1, cT = rem & 1;
    int hw0 = hwT * 32, c0 = cT * 128;
    int tid = threadIdx.x;
    const float* src = x + (size_t)b * C_ * HW_;
    {
        int hwi = tid & 31, cr = tid >> 5;
#pragma unroll
        for (int ps = 0; ps < 16; ++ps) {
            int c = cr + ps * 8;
            t[hwi][c] = src[(size_t)(c0 + c) * HW_ + hw0 + hwi];
        }
    }
    __syncthreads();
    {
        int c4 = (tid & 31) * 4, hwr = tid >> 5;
        unsigned short* dst = xT + (size_t)(((b << 12) + hw0) * 256) + c0 + c4;
#pragma unroll
        for (int ps = 0; ps < 4; ++ps) {
            int hw = hwr + ps * 8;
            f32x4 v = *(const f32x4*)&t[hw][c4];
            ushort4 u;
            u.x = f2bf(v.x); u.y = f2bf(v.y); u.z = f2bf(v.z); u.w = f2bf(v.w);
            *(ushort4*)(dst + (size_t)hw * 256) = u;
        }
    }
}

// ---------------- K2: offsets — 1-wave blocks, barrier-free ---------------------------
__launch_bounds__(64)
__global__ void k_offsets(const unsigned short* __restrict__ xT,
                          const float* __restrict__ dwc_w,
                          const float* __restrict__ ln_w,
                          const float* __restrict__ ln_b,
                          const float* __restrict__ fcd_w,
                          const float* __restrict__ fca_w,
                          float* __restrict__ OX, float* __restrict__ OY)
{
    int bi = blockIdx.x;                       // 1024 blocks of 16 positions
    int q = ((bi & 7) << 7) | (bi >> 3);       // XCD swizzle (matches k_main ownership)
    int b = q >> 8;
    int rem = q & 255;
    int y = rem >> 2, xq = (rem & 3) << 4;
    int lane = threadIdx.x;
    int c4 = lane << 2;

    float w[9][4];
#pragma unroll
    for (int i = 0; i < 4; ++i)
#pragma unroll
        for (int j = 0; j < 9; ++j) w[j][i] = dwc_w[(c4 + i) * 9 + j];
    float lw[4], lb[4], fd[4], fa[4];
#pragma unroll
    for (int i = 0; i < 4; ++i) {
        lw[i] = ln_w[c4 + i]; lb[i] = ln_b[c4 + i];
        fd[i] = fcd_w[c4 + i]; fa[i] = fca_w[c4 + i];
    }
    const unsigned short* xbb = xT + ((size_t)b << 12) * 256;

    for (int p = 0; p < 16; ++p) {
        int xx = xq + p;
        float acc[4] = {0.f, 0.f, 0.f, 0.f};
#pragma unroll
        for (int j = 0; j < 9; ++j) {
            int gy = y + j / 3 - 1, gx = xx + j % 3 - 1;
            if (gy >= 0 && gy < H_ && gx >= 0 && gx < W_) {
                ushort4 v = *(const ushort4*)(xbb + ((size_t)((gy << 6) + gx)) * 256 + c4);
                acc[0] += w[j][0] * bf2f(v.x);
                acc[1] += w[j][1] * bf2f(v.y);
                acc[2] += w[j][2] * bf2f(v.z);
                acc[3] += w[j][3] * bf2f(v.w);
            }
        }
        float s1 = acc[0] + acc[1] + acc[2] + acc[3];
        float s2 = acc[0]*acc[0] + acc[1]*acc[1] + acc[2]*acc[2] + acc[3]*acc[3];
#pragma unroll
        for (int m = 1; m <= 32; m <<= 1) {
            s1 += __shfl_xor(s1, m);
            s2 += __shfl_xor(s2, m);
        }
        float mu  = s1 * (1.f / 256.f);
        float var = s2 * (1.f / 256.f) - mu * mu;
        float rs = rsqrtf(var + 1e-5f);
        float d1 = 0.f, d2 = 0.f;
#pragma unroll
        for (int i = 0; i < 4; ++i) {
            float hn = (acc[i] - mu) * rs * lw[i] + lb[i];
            hn = fmaxf(hn, 0.f);
            d1 += hn * fd[i];
            d2 += hn * fa[i];
        }
#pragma unroll
        for (int m = 1; m <= 32; m <<= 1) {
            d1 += __shfl_xor(d1, m);
            d2 += __shfl_xor(d2, m);
        }
        if (lane == 0) {
            float r0 = fmaxf(d1, 0.f);
            float theta = d2 / (1.f + fabsf(d2)) * 0.017453292519943295f;
            int pos = (((b << 6) + y) << 6) + xx;
            OX[pos] = r0 * cosf(theta);
            OY[pos] = r0 * sinf(theta);
        }
    }
}

// ---------------- K3: pack dconv_w (Co,C,3,3) f32 -> Bt (N=256 x K=2304) bf16 --------
__global__ void k_packB(const float* __restrict__ w, unsigned short* __restrict__ Bt)
{
    int idx = blockIdx.x * 256 + threadIdx.x;
    int o = idx / 2304, kk = idx - o * 2304;
    int k = kk >> 8, c = kk & 255;
    Bt[idx] = f2bf(w[(o * C_ + c) * 9 + k]);
}

// ---------------- K4: implicit GEMM deformable conv ----------------------------------
// 512 blocks (XCD-swizzled, 32 positions), 512 threads = 8 waves.
// B-fragments register-double-buffered at half-tap granularity; gather split lo/hi.
__launch_bounds__(512, 4)
__global__ void k_main(const unsigned short* __restrict__ xT,
                       const float* __restrict__ OX, const float* __restrict__ OY,
                       const unsigned short* __restrict__ Bt,
                       const float* __restrict__ bias,
                       float* __restrict__ out)
{
    __shared__ __align__(16) unsigned char smem[32768];  // A dbuf 2x16KB / epilogue 32KB
    __shared__ float OXs[32], OYs[32];
    float* epi = (float*)smem;

    int tid = threadIdx.x;
    int bi = blockIdx.x;
    int swz = ((bi & 7) << 6) | (bi >> 3);
    int p0 = swz << 5;
    int b = p0 >> 12;
    int y = (p0 >> 6) & 63;
    int xh = p0 & 63;
    if (tid < 32) { OXs[tid] = OX[p0 + tid]; OYs[tid] = OY[p0 + tid]; }

    int lane = tid & 63, wid = tid >> 6;
    int l15 = lane & 15, l4 = lane >> 4;

    f32x4 acc[2][2];
#pragma unroll
    for (int m = 0; m < 2; ++m)
#pragma unroll
        for (int n = 0; n < 2; ++n) {
            acc[m][n].x = 0.f; acc[m][n].y = 0.f; acc[m][n].z = 0.f; acc[m][n].w = 0.f;
        }

    int gpos = tid >> 4;              // 0..31 position
    int cblk = (tid & 15) << 4;       // 16-channel chunk
    const unsigned short* xb = xT + (size_t)b * HW_ * C_;
    const unsigned short* brow = Bt + (size_t)(wid * 32 + l15) * 2304 + (l4 << 3);
    unsigned swzr = ((unsigned)gpos & 7u) << 4;
    unsigned rowb = (unsigned)gpos * 512u;

    __syncthreads();
    float ox = OXs[gpos], oy = OYs[gpos];

    // compute 32-bit corner offsets + weights for tap k
#define GADDR(k)                                                                  \
        int ky = (k) / 3, kx = (k) - ky * 3;                                      \
        float dyv = ((k) <= 4) ? ox : oy;                                         \
        float dxv = ((k) <= 3) ? ox : oy;                                         \
        float py = (float)(y - 1 + ky) + dyv;                                     \
        float px = (float)(xh + gpos - 1 + kx) + dxv;                             \
        float y0f = floorf(py), x0f = floorf(px);                                 \
        int y0 = (int)y0f, x0 = (int)x0f;                                         \
        int y1 = y0 + 1, x1 = x0 + 1;                                             \
        float wy1 = py - y0f, wy0 = 1.f - wy1;                                    \
        float wx1 = px - x0f, wx0 = 1.f - wx1;                                    \
        float vy0 = (y0 >= 0 && y0 < H_) ? 1.f : 0.f;                             \
        float vy1 = (y1 >= 0 && y1 < H_) ? 1.f : 0.f;                             \
        float vx0 = (x0 >= 0 && x0 < W_) ? 1.f : 0.f;                             \
        float vx1 = (x1 >= 0 && x1 < W_) ? 1.f : 0.f;                             \
        w00 = wy0 * wx0 * vy0 * vx0; w01 = wy0 * wx1 * vy0 * vx1;                 \
        w10 = wy1 * wx0 * vy1 * vx0; w11 = wy1 * wx1 * vy1 * vx1;                 \
        int y0c = min(max(y0, 0), H_ - 1), y1c = min(max(y1, 0), H_ - 1);         \
        int x0c = min(max(x0, 0), W_ - 1), x1c = min(max(x1, 0), W_ - 1);         \
        o00 = (unsigned)((y0c << 6) + x0c) * 256u + (unsigned)cblk;               \
        o01 = (unsigned)((y0c << 6) + x1c) * 256u + (unsigned)cblk;               \
        o10 = (unsigned)((y1c << 6) + x0c) * 256u + (unsigned)cblk;               \
        o11 = (unsigned)((y1c << 6) + x1c) * 256u + (unsigned)cblk;

#define GLOAD(G, add)                                                             \
        G[0] = *(const short8*)(xb + o00 + (add));                                \
        G[1] = *(const short8*)(xb + o01 + (add));                                \
        G[2] = *(const short8*)(xb + o10 + (add));                                \
        G[3] = *(const short8*)(xb + o11 + (add));

#define LERP8(G, add, buf)                                                        \
    {   short8 res;                                                               \
        _Pragma("unroll")                                                         \
        for (int j = 0; j < 8; ++j) {                                             \
            float a = bf2f((unsigned short)G[0][j]) * w00                         \
                    + bf2f((unsigned short)G[1][j]) * w01                         \
                    + bf2f((unsigned short)G[2][j]) * w10                         \
                    + bf2f((unsigned short)G[3][j]) * w11;                        \
            res[j] = (short)f2bf(a);                                              \
        }                                                                         \
        *(short8*)(smem + (unsigned)(buf) * 16384u + rowb +                       \
                   ((((unsigned)(cblk + (add))) * 2u) ^ swzr)) = res;             \
    }

#define LOADB(dst, kk, h)                                                         \
    _Pragma("unroll")                                                             \
    for (int i = 0; i < 8; ++i) {                                                 \
        int ks = (h) * 4 + (i >> 1), n = i & 1;                                   \
        dst[i] = *(const short8*)(brow + ((kk) << 8) + ks * 32 + n * (16 * 2304));\
    }

#define MFMA_HALF(h, Bq, t)                                                       \
    {   unsigned abase = (unsigned)(t) * 16384u;                                  \
        _Pragma("unroll")                                                         \
        for (int ks2 = 0; ks2 < 4; ++ks2) {                                       \
            int ks = (h) * 4 + ks2;                                               \
            unsigned coff = (unsigned)(ks * 64 + (l4 << 4)) ^                     \
                            (((unsigned)l15 & 7u) << 4);                          \
            short8 a0 = *(const short8*)(smem + abase + (unsigned)l15 * 512u + coff);        \
            short8 a1 = *(const short8*)(smem + abase + (unsigned)(16 + l15) * 512u + coff); \
            acc[0][0] = __builtin_amdgcn_mfma_f32_16x16x32_bf16(a0, Bq[ks2*2+0], acc[0][0], 0, 0, 0); \
            acc[0][1] = __builtin_amdgcn_mfma_f32_16x16x32_bf16(a0, Bq[ks2*2+1], acc[0][1], 0, 0, 0); \
            acc[1][0] = __builtin_amdgcn_mfma_f32_16x16x32_bf16(a1, Bq[ks2*2+0], acc[1][0], 0, 0, 0); \
            acc[1][1] = __builtin_amdgcn_mfma_f32_16x16x32_bf16(a1, Bq[ks2*2+1], acc[1][1], 0, 0, 0); \
        } }

    short8 B0[8], B1[8];

    // ---- prologue: gather tap 0 into buf0, prefetch B(tap0, half0) ----
    {
        unsigned o00, o01, o10, o11;
        float w00, w01, w10, w11;
        GADDR(0);
        short8 glo[4], ghi[4];
        GLOAD(glo, 0);
        GLOAD(ghi, 8);
        LERP8(glo, 0, 0);
        LERP8(ghi, 8, 0);
    }
    LOADB(B0, 0, 0);
    __syncthreads();

#pragma unroll
    for (int k = 0; k < 9; ++k) {
        int t = k & 1;
        LOADB(B1, k, 1);                          // B half1 of this tap
        unsigned o00, o01, o10, o11;
        float w00, w01, w10, w11;
        short8 glo[4], ghi[4];
        if (k < 8) {
            GADDR(k + 1);
            GLOAD(glo, 0);                        // gather lo early
        }
        MFMA_HALF(0, B0, t);
        if (k < 8) {
            LOADB(B0, k + 1, 0);                  // prefetch next tap's B half0
            LERP8(glo, 0, t ^ 1);                 // lerp lo (waits its loads)
            GLOAD(ghi, 8);                        // gather hi
        }
        MFMA_HALF(1, B1, t);
        if (k < 8) {
            LERP8(ghi, 8, t ^ 1);
        }
        __syncthreads();
    }

    // ---- epilogue ----
#pragma unroll
    for (int m = 0; m < 2; ++m)
#pragma unroll
        for (int n = 0; n < 2; ++n)
#pragma unroll
            for (int i = 0; i < 4; ++i) {
                int row = m * 16 + l4 * 4 + i;
                int col = wid * 32 + n * 16 + l15;
                epi[row * 256 + col] = acc[m][n][i];
            }
    __syncthreads();
    int o = tid >> 1;
    int wb = (tid & 1) << 4;
    float bv = bias[o];
    float* orow = out + (size_t)(((b * CO_ + o) * H_ + y) * W_) + xh + wb;
#pragma unroll
    for (int w4 = 0; w4 < 16; w4 += 4) {
        f32x4 v;
        v.x = epi[(wb + w4 + 0) * 256 + o] + bv;
        v.y = epi[(wb + w4 + 1) * 256 + o] + bv;
        v.z = epi[(wb + w4 + 2) * 256 + o] + bv;
        v.w = epi[(wb + w4 + 3) * 256 + o] + bv;
        *(f32x4*)(orow + w4) = v;
    }
}

extern "C" void kernel_launch(void* const* d_in, const int* in_sizes, int n_in,
                              void* d_out, int out_size, void* d_ws, size_t ws_size,
                              hipStream_t stream) {
    const float* x      = (const float*)d_in[0];
    const float* dwc_w  = (const float*)d_in[1];
    const float* ln_w   = (const float*)d_in[2];
    const float* ln_b   = (const float*)d_in[3];
    const float* fcd_w  = (const float*)d_in[4];
    const float* fca_w  = (const float*)d_in[5];
    const float* dconv_w= (const float*)d_in[6];
    const float* dconv_b= (const float*)d_in[7];
    float* out = (float*)d_out;

    unsigned char* ws = (unsigned char*)d_ws;
    unsigned short* xT = (unsigned short*)(ws);                 // 8 MB bf16 NHWC
    float* OX = (float*)(ws + 8388608);
    float* OY = (float*)(ws + 8454144);
    unsigned short* Bt = (unsigned short*)(ws + 8519680);

    k_transpose<<<1024, 256, 0, stream>>>(x, xT);
    k_packB<<<2304, 256, 0, stream>>>(dconv_w, Bt);
    k_offsets<<<1024, 64, 0, stream>>>(xT, dwc_w, ln_w, ln_b, fcd_w, fca_w, OX, OY);
    k_main<<<512, 512, 0, stream>>>(xT, OX, OY, Bt, dconv_b, out);
}